// Round 6
// baseline (482.056 us; speedup 1.0000x reference)
//
#include <hip/hip_runtime.h>
#include <math.h>

#define N_DIM 1000
#define P_DIM 50000
#define Z_DIM 10
#define L_DIM 5
#define NSTEP 50

// precompute grid
#define NTP 256
#define NBP 196          // ceil(50000/256)
#define NSPLIT 4
#define NCHUNK 250       // N_DIM / NSPLIT

// step kernel: 25 blocks x 320 threads. Wave 0 = DEDICATED poller/merger: its vmem
// queue holds ONLY the poll loads, so its s_waitcnt never drains store-acks or
// prefetch loads (the r5 flaw). Waves 1-4 compute 512 p each (2048 p/block,
// 25*2048 = 51200 >= 50000) and spin on an LDS slot (lgkmcnt-only, decoupled).
#define NT1 320
#define PPT 8
#define PBLK 2048
#define NBLK 25
#define NPUB 100             // publisher waves = 25 blocks x 4 compute waves
#define SLOT_STRIDE 128      // u64 slots reserved per step (100 used)
#define NEG_BIG (-3.0e38f)
#define SPIN_MAX 65536       // bounded spins: sync failure -> wrong result, not a hang
#define SPIN_MAX_LDS (1 << 20)

// ---- workspace layout (floats) ----
constexpr size_t ZP       = (size_t)Z_DIM * P_DIM;            // 500000
constexpr size_t OFF_PART = 0;                                // u64[NSTEP*SLOT_STRIDE]
constexpr size_t PART_F   = (size_t)NSTEP * SLOT_STRIDE * 2;  // in floats (12800)
constexpr size_t OFF_ZTRP = PART_F;                           // [NSPLIT][Z][P] (no atomics)
constexpr size_t OFF_W    = OFF_ZTRP + (size_t)NSPLIT * ZP;   // [Z][P] W0
constexpr size_t OFF_ZZ   = OFF_W + ZP;                       // [Z*Z], reserve 128

// ---- output layout (floats) ----
constexpr size_t OUT_MW = 0;
constexpr size_t OUT_VW = (size_t)L_DIM * Z_DIM * P_DIM;      // 2,500,000
constexpr size_t OUT_AL = OUT_VW + (size_t)L_DIM * Z_DIM;     // 2,500,050

// Fused precompute (one launch, grid y = NSPLIT+1 rows):
//  rows 0..NSPLIT-1 : ZtRp[y][z][p] = chunk-y of mean_z^T @ data (plain stores)
//                     + W0[z][p] on row 0
//  row  NSPLIT      : bx < 100       -> zz[bx] = mean_z^T mean_z + N*var_z
//                     bx in [100,196)-> zero the NSTEP*SLOT_STRIDE partial slots
__global__ __launch_bounds__(NTP) void precompute_big(const float* __restrict__ data,
                                                      const float* __restrict__ mean_z,
                                                      const float* __restrict__ var_z,
                                                      const float* __restrict__ mw0,
                                                      const float* __restrict__ al0,
                                                      float* __restrict__ ws) {
    if (blockIdx.y == NSPLIT) {
        int bx = blockIdx.x;
        if (bx < Z_DIM * Z_DIM) {
            float* zz = ws + OFF_ZZ;
            int i = bx / Z_DIM, j = bx % Z_DIM;
            float s = 0.f;
            for (int n = threadIdx.x; n < N_DIM; n += NTP)
                s += mean_z[n * Z_DIM + i] * mean_z[n * Z_DIM + j];
            #pragma unroll
            for (int off = 32; off > 0; off >>= 1) s += __shfl_xor(s, off);
            __shared__ float ls[4];
            if ((threadIdx.x & 63) == 0) ls[threadIdx.x >> 6] = s;
            __syncthreads();
            if (threadIdx.x == 0) {
                float t = ls[0] + ls[1] + ls[2] + ls[3];
                zz[bx] = t + (float)N_DIM * var_z[bx];
            }
        } else {
            // zero partial slots (ws is poisoned 0xAA; poisoned slots look "ready")
            unsigned long long* part = reinterpret_cast<unsigned long long*>(ws + OFF_PART);
            int idx = (bx - Z_DIM * Z_DIM) * NTP + threadIdx.x;
            if (idx < NSTEP * SLOT_STRIDE) part[idx] = 0ULL;
        }
        return;
    }

    float* ZtRp = ws + OFF_ZTRP + (size_t)blockIdx.y * ZP;
    float* W    = ws + OFF_W;
    __shared__ float mzs[NCHUNK * Z_DIM];   // 10 KB
    int n0 = blockIdx.y * NCHUNK;
    for (int i = threadIdx.x; i < NCHUNK * Z_DIM; i += NTP)
        mzs[i] = mean_z[n0 * Z_DIM + i];
    __syncthreads();
    int p = blockIdx.x * NTP + threadIdx.x;
    if (p >= P_DIM) return;

    float acc[Z_DIM];
    #pragma unroll
    for (int z = 0; z < Z_DIM; z++) acc[z] = 0.f;
    for (int r = 0; r < NCHUNK; r++) {
        float d = data[(size_t)(n0 + r) * P_DIM + p];
        #pragma unroll
        for (int z = 0; z < Z_DIM; z++) acc[z] = fmaf(mzs[r * Z_DIM + z], d, acc[z]);
    }
    #pragma unroll
    for (int z = 0; z < Z_DIM; z++) ZtRp[(size_t)z * P_DIM + p] = acc[z];

    if (blockIdx.y == 0) {
        #pragma unroll
        for (int z = 0; z < Z_DIM; z++) {
            float w = 0.f;
            #pragma unroll
            for (int l = 0; l < L_DIM; l++) {
                size_t io = ((size_t)l * Z_DIM + z) * P_DIM + p;
                w = fmaf(mw0[io], al0[io], w);
            }
            W[(size_t)z * P_DIM + p] = w;
        }
    }
}

__device__ inline float4 ld4(const float* p) { return *reinterpret_cast<const float4*>(p); }

// All 50 (k,l) steps in one persistent kernel. E_s is affine in scale_{s-1}
// (E = E_base - h*scale), so the post-detect critical path is just
// exp/div -> 2 FMA/p -> max-reduce -> exp -> sum-reduce -> publish; everything
// else (stores, W/r updates, next E_base/h, input loads) runs in the poll window.
__global__ __launch_bounds__(NT1, 2) void steps_fused(const float* __restrict__ mw0,
                                                      const float* __restrict__ al0,
                                                      const float* __restrict__ pi,
                                                      const float* __restrict__ tau0,
                                                      const float* __restrict__ taup,
                                                      float* __restrict__ ws,
                                                      float* __restrict__ out) {
    const float* ZtRp = ws + OFF_ZTRP;
    const float* Wg   = ws + OFF_W;
    const float* zz   = ws + OFF_ZZ;
    unsigned long long* part = reinterpret_cast<unsigned long long*>(ws + OFF_PART);
    float* out_mw = out + OUT_MW;
    float* out_vw = out + OUT_VW;
    float* out_al = out + OUT_AL;

    __shared__ unsigned long long lsl[NSTEP];   // write-once per step: packed (M, ss)

    const int tid  = threadIdx.x;
    const int bid  = blockIdx.x;
    const int lane = tid & 63;
    const int wid  = tid >> 6;
    const float tau = taup[0];

    for (int i = tid; i < NSTEP; i += NT1) lsl[i] = 0ULL;
    __syncthreads();                      // only barrier in the whole kernel

    if (wid == 0) {
        // ================= dedicated poller wave =================
        // vmem queue = poll loads ONLY -> waitcnt never drains unrelated traffic.
        const unsigned long long READY0 =
            ((unsigned long long)1u << 32) | (unsigned long long)__float_as_uint(NEG_BIG);
        const bool has2 = lane < (NPUB - 64);     // lanes 0..35 own slots 64..99
        for (int s = 0; s < NSTEP; s++) {
            const unsigned long long* sb = part + (size_t)s * SLOT_STRIDE;
            unsigned long long v0 = 0, v1 = READY0;
            for (int it = 0; it < SPIN_MAX; it++) {
                // re-load both every probe (slots are write-once: re-read is safe);
                // independent loads pipeline -> sampling period ~ issue gap, not RT
                v0 = __hip_atomic_load(sb + lane, __ATOMIC_RELAXED, __HIP_MEMORY_SCOPE_AGENT);
                if (has2)
                    v1 = __hip_atomic_load(sb + 64 + lane, __ATOMIC_RELAXED, __HIP_MEMORY_SCOPE_AGENT);
                if ((unsigned)(v0 >> 32) && (unsigned)(v1 >> 32)) break;
            }
            float m0 = __uint_as_float((unsigned)v0), e0 = __uint_as_float((unsigned)(v0 >> 32));
            float m1 = __uint_as_float((unsigned)v1), e1 = __uint_as_float((unsigned)(v1 >> 32));
            float mm = fmaxf(m0, m1);
            #pragma unroll
            for (int off = 32; off > 0; off >>= 1) mm = fmaxf(mm, __shfl_xor(mm, off));
            float ss = e0 * __expf(m0 - mm) + e1 * __expf(m1 - mm);
            #pragma unroll
            for (int off = 32; off > 0; off >>= 1) ss += __shfl_xor(ss, off);
            if (lane == 0) {
                unsigned long long v = ((unsigned long long)__float_as_uint(ss) << 32)
                                     | (unsigned long long)__float_as_uint(mm);
                __hip_atomic_store(&lsl[s], v, __ATOMIC_RELAXED, __HIP_MEMORY_SCOPE_WORKGROUP);
                if (bid == 0) {
                    int k = s / L_DIM, l = s % L_DIM;
                    out_vw[l * Z_DIM + k] = 1.f / fmaf(tau, zz[k * Z_DIM + k], tau0[l * Z_DIM + k]);
                }
            }
        }
        return;
    }

    // ================= compute waves (1..4) =================
    const int cw = wid - 1;
    const int p0 = bid * PBLK + (cw * 64 + lane) * PPT;   // P%8==0 -> all-or-none valid
    const bool valid = p0 < P_DIM;

    float W[Z_DIM][PPT];
    #pragma unroll
    for (int z = 0; z < Z_DIM; z++)
        #pragma unroll
        for (int i = 0; i < PPT; i++) W[z][i] = 0.f;
    float mw_c[PPT], al_c[PPT], lpi[PPT];
    #pragma unroll
    for (int i = 0; i < PPT; i++) { mw_c[i] = 0.f; al_c[i] = 0.f; lpi[i] = 0.f; }
    float r[PPT], E_base[PPT], h[PPT];
    #pragma unroll
    for (int i = 0; i < PPT; i++) { r[i] = 0.f; E_base[i] = 0.f; h[i] = 0.f; }

    if (valid) {
        #pragma unroll
        for (int z = 0; z < Z_DIM; z++) {
            float4 a = ld4(Wg + (size_t)z * P_DIM + p0);
            float4 b = ld4(Wg + (size_t)z * P_DIM + p0 + 4);
            W[z][0]=a.x; W[z][1]=a.y; W[z][2]=a.z; W[z][3]=a.w;
            W[z][4]=b.x; W[z][5]=b.y; W[z][6]=b.z; W[z][7]=b.w;
        }
        float4 ma = ld4(mw0 + p0), mb = ld4(mw0 + p0 + 4);   // step 0 = (k=0,l=0)
        float4 aa = ld4(al0 + p0), ab = ld4(al0 + p0 + 4);
        mw_c[0]=ma.x; mw_c[1]=ma.y; mw_c[2]=ma.z; mw_c[3]=ma.w;
        mw_c[4]=mb.x; mw_c[5]=mb.y; mw_c[6]=mb.z; mw_c[7]=mb.w;
        al_c[0]=aa.x; al_c[1]=aa.y; al_c[2]=aa.z; al_c[3]=aa.w;
        al_c[4]=ab.x; al_c[5]=ab.y; al_c[6]=ab.z; al_c[7]=ab.w;
        float4 pa = ld4(pi + p0), pb = ld4(pi + p0 + 4);
        lpi[0]=__logf(pa.x); lpi[1]=__logf(pa.y); lpi[2]=__logf(pa.z); lpi[3]=__logf(pa.w);
        lpi[4]=__logf(pb.x); lpi[5]=__logf(pb.y); lpi[6]=__logf(pb.z); lpi[7]=__logf(pb.w);
        #pragma unroll
        for (int y = 0; y < NSPLIT; y++) {                    // Zt[k=0]
            const float* src = ZtRp + ((size_t)y * Z_DIM + 0) * P_DIM + p0;
            float4 a = ld4(src), b = ld4(src + 4);
            r[0]+=a.x; r[1]+=a.y; r[2]+=a.z; r[3]+=a.w;
            r[4]+=b.x; r[5]+=b.y; r[6]+=b.z; r[7]+=b.w;
        }
    }
    // factor-0 residual + step-0 E_base (window "-1")
    #pragma unroll
    for (int j = 1; j < Z_DIM; j++) {                         // j==0 excluded
        float c = zz[j];
        #pragma unroll
        for (int i = 0; i < PPT; i++) r[i] = fmaf(-c, W[j][i], r[i]);
    }
    float Ezz = zz[0], t0v = tau0[0];
    float tuv = tau / fmaf(tau, Ezz, t0v);                    // tau * u_var
    float s2 = 1.f / (Ezz * tau), s0i = 1.f / t0v;
    float cq = 0.5f * (tau / Ezz) * (s0i / (s2 + s0i));
    #pragma unroll
    for (int i = 0; i < PPT; i++) {
        float wklA = W[0][i] - mw_c[i] * al_c[i];
        E_base[i] = fmaf(-Ezz, wklA, r[i]);                   // h[i] = 0 (scale=1 at s=0)
    }

    float wklP[PPT], ccP[PPT], esvP[PPT];
    #pragma unroll
    for (int i = 0; i < PPT; i++) { wklP[i] = 0.f; ccP[i] = 0.f; esvP[i] = 0.f; }
    float MwP = 0.f, scale = 1.f;
    int io_prev = 0;
    int k = 0, l = 0;
    const int gw = bid * 4 + cw;

    #pragma unroll 1
    for (int s = 0; s < NSTEP; s++) {
        // ---- detect scale_{s-1} via LDS (lgkmcnt only; vmem queue untouched) ----
        if (s > 0) {
            unsigned long long v = 0;
            for (int it = 0; it < SPIN_MAX_LDS; it++) {
                v = __hip_atomic_load(&lsl[s - 1], __ATOMIC_RELAXED, __HIP_MEMORY_SCOPE_WORKGROUP);
                if ((unsigned)(v >> 32)) break;
            }
            float M  = __uint_as_float((unsigned)v);
            float ss = __uint_as_float((unsigned)(v >> 32));
            scale = __expf(MwP - M) / ss;
        }

        // ---- minimal pre-publish path: 2 FMA/p -> reduce -> exp -> reduce ----
        float Ev[PPT], lgt[PPT], esv[PPT];
        #pragma unroll
        for (int i = 0; i < PPT; i++) {
            Ev[i]  = fmaf(-h[i], scale, E_base[i]);
            lgt[i] = valid ? fmaf(cq * Ev[i], Ev[i], lpi[i]) : NEG_BIG;
        }
        float m4 = lgt[0];
        #pragma unroll
        for (int i = 1; i < PPT; i++) m4 = fmaxf(m4, lgt[i]);
        #pragma unroll
        for (int off = 32; off > 0; off >>= 1) m4 = fmaxf(m4, __shfl_xor(m4, off));
        const float Mw = m4;
        float s4 = 0.f;
        #pragma unroll
        for (int i = 0; i < PPT; i++) { esv[i] = __expf(lgt[i] - Mw); s4 += esv[i]; }
        #pragma unroll
        for (int off = 32; off > 0; off >>= 1) s4 += __shfl_xor(s4, off);
        if (lane == 0) {
            // valid wave: Ew>=1. fully-invalid wave: Mw=NEG_BIG, esv=1 -> Ew=512,
            // contributes Ew*exp(Mw-M)=0 in the merge. hi word != 0 either way.
            unsigned long long v = ((unsigned long long)__float_as_uint(s4) << 32)
                                 | (unsigned long long)__float_as_uint(Mw);
            __hip_atomic_store(&part[(size_t)s * SLOT_STRIDE + gw], v, __ATOMIC_RELAXED,
                               __HIP_MEMORY_SCOPE_AGENT);
        }

        // ================== poll window (deferred work) ==================
        const int io_s = (l * Z_DIM + k) * P_DIM + p0;
        int kn = k, ln = l + 1;
        if (ln == L_DIM) { ln = 0; kn++; }
        const bool more = (s + 1 < NSTEP);
        const bool bnd  = more && (ln == 0);

        // W1: issue step-(s+1) input loads (consumed at window end -> latency hidden)
        float mw_n[PPT], al_n[PPT];
        #pragma unroll
        for (int i = 0; i < PPT; i++) { mw_n[i] = 0.f; al_n[i] = 0.f; }
        float pin[PPT], zkn[PPT];
        #pragma unroll
        for (int i = 0; i < PPT; i++) { pin[i] = 1.f; zkn[i] = 0.f; }
        if (valid && more) {
            size_t ion = ((size_t)ln * Z_DIM + kn) * P_DIM + p0;
            float4 ma = ld4(mw0 + ion), mb = ld4(mw0 + ion + 4);
            float4 aa = ld4(al0 + ion), ab = ld4(al0 + ion + 4);
            mw_n[0]=ma.x; mw_n[1]=ma.y; mw_n[2]=ma.z; mw_n[3]=ma.w;
            mw_n[4]=mb.x; mw_n[5]=mb.y; mw_n[6]=mb.z; mw_n[7]=mb.w;
            al_n[0]=aa.x; al_n[1]=aa.y; al_n[2]=aa.z; al_n[3]=aa.w;
            al_n[4]=ab.x; al_n[5]=ab.y; al_n[6]=ab.z; al_n[7]=ab.w;
            if (bnd) {
                float4 pa = ld4(pi + (size_t)kn * P_DIM + p0);
                float4 pb = ld4(pi + (size_t)kn * P_DIM + p0 + 4);
                pin[0]=pa.x; pin[1]=pa.y; pin[2]=pa.z; pin[3]=pa.w;
                pin[4]=pb.x; pin[5]=pb.y; pin[6]=pb.z; pin[7]=pb.w;
                #pragma unroll
                for (int y = 0; y < NSPLIT; y++) {
                    const float* src = ZtRp + ((size_t)y * Z_DIM + kn) * P_DIM + p0;
                    float4 a = ld4(src), b = ld4(src + 4);
                    zkn[0]+=a.x; zkn[1]+=a.y; zkn[2]+=a.z; zkn[3]+=a.w;
                    zkn[4]+=b.x; zkn[5]+=b.y; zkn[6]+=b.z; zkn[7]+=b.w;
                }
            }
        }

        // W2: finalize step s-1's alpha (needs scale_{s-1} = current scale)
        if (valid && s > 0) {
            float a[PPT];
            #pragma unroll
            for (int i = 0; i < PPT; i++) a[i] = esvP[i] * scale;
            *reinterpret_cast<float4*>(out_al + io_prev)     = make_float4(a[0],a[1],a[2],a[3]);
            *reinterpret_cast<float4*>(out_al + io_prev + 4) = make_float4(a[4],a[5],a[6],a[7]);
        }

        // W3: wkl_s + deferred W/r writebacks
        float wkl_s[PPT];
        if (l == 0) {
            if (s > 0) {
                #pragma unroll
                for (int j = 0; j < Z_DIM; j++)                 // static-index writeback W[k-1]
                    if (j == k - 1)
                        #pragma unroll
                        for (int i = 0; i < PPT; i++) W[j][i] = fmaf(ccP[i], scale, wklP[i]);
                #pragma unroll
                for (int i = 0; i < PPT; i++) r[i] = fmaf(-h[i], scale, r[i]);  // pending -g*scale
            }
            float wkr[PPT];
            #pragma unroll
            for (int i = 0; i < PPT; i++) wkr[i] = 0.f;
            #pragma unroll
            for (int j = 0; j < Z_DIM; j++)
                if (j == k)
                    #pragma unroll
                    for (int i = 0; i < PPT; i++) wkr[i] = W[j][i];
            #pragma unroll
            for (int i = 0; i < PPT; i++) wkl_s[i] = wkr[i] - mw_c[i] * al_c[i];
        } else {
            #pragma unroll
            for (int i = 0; i < PPT; i++)
                wkl_s[i] = fmaf(ccP[i], scale, wklP[i]) - mw_c[i] * al_c[i];
        }

        // W4: u_mean store + cc
        float cc_s[PPT];
        #pragma unroll
        for (int i = 0; i < PPT; i++) cc_s[i] = 0.f;
        if (valid) {
            float um[PPT];
            #pragma unroll
            for (int i = 0; i < PPT; i++) um[i] = tuv * Ev[i];
            *reinterpret_cast<float4*>(out_mw + io_s)     = make_float4(um[0],um[1],um[2],um[3]);
            *reinterpret_cast<float4*>(out_mw + io_s + 4) = make_float4(um[4],um[5],um[6],um[7]);
            #pragma unroll
            for (int i = 0; i < PPT; i++) cc_s[i] = um[i] * esv[i];
        }

        // W5: step-(s+1) scalars + E_base/h
        if (more) {
            float Ezz_n = zz[kn * Z_DIM + kn], t0v_n = tau0[ln * Z_DIM + kn];
            float tuv_n = tau / fmaf(tau, Ezz_n, t0v_n);
            float s2n = 1.f / (Ezz_n * tau), s0in = 1.f / t0v_n;
            float cq_n = 0.5f * (tau / Ezz_n) * (s0in / (s2n + s0in));
            if (!bnd) {
                #pragma unroll
                for (int i = 0; i < PPT; i++) {
                    E_base[i] = fmaf(-Ezz_n, wkl_s[i] - mw_n[i] * al_n[i], r[i]);
                    h[i]      = Ezz_n * cc_s[i];
                }
            } else {
                float zkk = zz[kn * Z_DIM + k];
                float rb[PPT];
                #pragma unroll
                for (int i = 0; i < PPT; i++) rb[i] = zkn[i];
                #pragma unroll
                for (int j = 0; j < Z_DIM; j++) {
                    float c = (j == kn || j == k) ? 0.f : zz[kn * Z_DIM + j];
                    #pragma unroll
                    for (int i = 0; i < PPT; i++) rb[i] = fmaf(-c, W[j][i], rb[i]);
                }
                #pragma unroll
                for (int i = 0; i < PPT; i++) {
                    rb[i] = fmaf(-zkk, wkl_s[i], rb[i]);   // old-W[k] part via wkl_s
                    r[i]  = rb[i];                          // r_base; -g*scale pending
                }
                float wA[PPT];
                #pragma unroll
                for (int i = 0; i < PPT; i++) wA[i] = 0.f;
                #pragma unroll
                for (int j = 0; j < Z_DIM; j++)
                    if (j == kn)
                        #pragma unroll
                        for (int i = 0; i < PPT; i++) wA[i] = W[j][i];
                #pragma unroll
                for (int i = 0; i < PPT; i++) {
                    wA[i] -= mw_n[i] * al_n[i];
                    E_base[i] = fmaf(-Ezz_n, wA[i], r[i]);
                    h[i]      = zkk * cc_s[i];
                    lpi[i]    = valid ? __logf(pin[i]) : 0.f;
                }
            }
            cq = cq_n; tuv = tuv_n;
        }

        // W6: shift state
        #pragma unroll
        for (int i = 0; i < PPT; i++) {
            esvP[i] = esv[i]; ccP[i] = cc_s[i]; wklP[i] = wkl_s[i];
            mw_c[i] = mw_n[i]; al_c[i] = al_n[i];
        }
        MwP = Mw; io_prev = io_s; k = kn; l = ln;
    }

    // epilogue: alpha for the last step needs scale_49
    {
        unsigned long long v = 0;
        for (int it = 0; it < SPIN_MAX_LDS; it++) {
            v = __hip_atomic_load(&lsl[NSTEP - 1], __ATOMIC_RELAXED, __HIP_MEMORY_SCOPE_WORKGROUP);
            if ((unsigned)(v >> 32)) break;
        }
        float M  = __uint_as_float((unsigned)v);
        float ss = __uint_as_float((unsigned)(v >> 32));
        float sc = __expf(MwP - M) / ss;
        if (valid) {
            float a[PPT];
            #pragma unroll
            for (int i = 0; i < PPT; i++) a[i] = esvP[i] * sc;
            *reinterpret_cast<float4*>(out_al + io_prev)     = make_float4(a[0],a[1],a[2],a[3]);
            *reinterpret_cast<float4*>(out_al + io_prev + 4) = make_float4(a[4],a[5],a[6],a[7]);
        }
    }
}

extern "C" void kernel_launch(void* const* d_in, const int* in_sizes, int n_in,
                              void* d_out, int out_size, void* d_ws, size_t ws_size,
                              hipStream_t stream) {
    (void)in_sizes; (void)n_in; (void)out_size; (void)ws_size;
    const float* data   = (const float*)d_in[0];
    const float* mean_z = (const float*)d_in[1];
    const float* var_z  = (const float*)d_in[2];
    const float* mw0    = (const float*)d_in[3];
    // d_in[4] var_w: unused (fully overwritten in output)
    const float* al0    = (const float*)d_in[5];
    const float* tau0   = (const float*)d_in[6];
    const float* pi     = (const float*)d_in[7];
    const float* taup   = (const float*)d_in[8];
    float* out = (float*)d_out;
    float* ws  = (float*)d_ws;

    // one fused precompute launch: ZtRp chunks + W0 + zz + partial-slot zeroing
    precompute_big<<<dim3(NBP, NSPLIT + 1), NTP, 0, stream>>>(data, mean_z, var_z,
                                                              mw0, al0, ws);
    steps_fused<<<NBLK, NT1, 0, stream>>>(mw0, al0, pi, tau0, taup, ws, out);
}